// Round 1
// baseline (3285.846 us; speedup 1.0000x reference)
//
#include <hip/hip_runtime.h>
#include <math.h>

// Problem constants
namespace {
constexpr int BB  = 8;     // batch
constexpr int CH  = 256;   // channels (v dim)
constexpr int CQ  = 32;    // q/k dim (C/8)
constexpr int NN  = 4096;  // H*W
constexpr int NF4 = NN / 4;
}

// ---------------------------------------------------------------------------
// Kernel 1: q/k/v projections (1x1 convs). One block per (b, 64-pixel tile).
// LDS-stage x tile [256][64]; thread (og=t/16, jq=t%16) computes output
// channels o = og*20+oo (o in [0,320): 0-31 q, 32-63 k, 64-319 v) for 4
// pixels jq*4..jq*4+3.
// ---------------------------------------------------------------------------
__global__ __launch_bounds__(256) void proj_kernel(
    const float* __restrict__ x,
    const float* __restrict__ wq, const float* __restrict__ bq,
    const float* __restrict__ wk, const float* __restrict__ bk,
    const float* __restrict__ wv, const float* __restrict__ bv,
    float* __restrict__ q, float* __restrict__ k, float* __restrict__ v)
{
    __shared__ float4 xt[CH * 16];  // 256 rows x 16 float4 = 64 KB
    const int t  = threadIdx.x;
    const int b  = blockIdx.x >> 6;
    const int n0 = (blockIdx.x & 63) << 6;

    const float4* xg = reinterpret_cast<const float4*>(x + (size_t)b * CH * NN + n0);
    for (int i = t; i < CH * 16; i += 256) {
        xt[i] = xg[(size_t)(i >> 4) * NF4 + (i & 15)];
    }
    __syncthreads();

    const int og = t >> 4;   // 0..15
    const int jq = t & 15;   // 0..15

    #pragma unroll 1
    for (int oo = 0; oo < 20; ++oo) {
        const int o = og * 20 + oo;   // 0..319, bijective
        const float* wrow;
        float bias;
        float* outp;
        if (o < 32) {
            wrow = wq + o * CH;        bias = bq[o];
            outp = q + ((size_t)b * CQ + o) * NN;
        } else if (o < 64) {
            wrow = wk + (o - 32) * CH; bias = bk[o - 32];
            outp = k + ((size_t)b * CQ + (o - 32)) * NN;
        } else {
            wrow = wv + (o - 64) * CH; bias = bv[o - 64];
            outp = v + ((size_t)b * CH + (o - 64)) * NN;
        }
        const float4* w4 = reinterpret_cast<const float4*>(wrow);
        float ax = 0.f, ay = 0.f, az = 0.f, aw = 0.f;
        #pragma unroll 4
        for (int c4 = 0; c4 < CH / 4; ++c4) {
            float4 wv4 = w4[c4];
            float4 x0 = xt[(c4 * 4 + 0) * 16 + jq];
            float4 x1 = xt[(c4 * 4 + 1) * 16 + jq];
            float4 x2 = xt[(c4 * 4 + 2) * 16 + jq];
            float4 x3 = xt[(c4 * 4 + 3) * 16 + jq];
            ax = fmaf(wv4.x, x0.x, ax); ax = fmaf(wv4.y, x1.x, ax);
            ax = fmaf(wv4.z, x2.x, ax); ax = fmaf(wv4.w, x3.x, ax);
            ay = fmaf(wv4.x, x0.y, ay); ay = fmaf(wv4.y, x1.y, ay);
            ay = fmaf(wv4.z, x2.y, ay); ay = fmaf(wv4.w, x3.y, ay);
            az = fmaf(wv4.x, x0.z, az); az = fmaf(wv4.y, x1.z, az);
            az = fmaf(wv4.z, x2.z, az); az = fmaf(wv4.w, x3.z, az);
            aw = fmaf(wv4.x, x0.w, aw); aw = fmaf(wv4.y, x1.w, aw);
            aw = fmaf(wv4.z, x2.w, aw); aw = fmaf(wv4.w, x3.w, aw);
        }
        float4 r;
        r.x = ax + bias; r.y = ay + bias; r.z = az + bias; r.w = aw + bias;
        reinterpret_cast<float4*>(outp + n0)[jq] = r;
    }
}

// ---------------------------------------------------------------------------
// Kernel 2: flash-style attention, two-pass softmax (exact).
// Block = (b, 64-query tile), 256 threads = 4 waves.
// Lane l owns query n0+l (all waves); wave w owns V channels [w*64, w*64+64).
// Pass 1: per-query exact (max, sum) with m-range split across waves
//         (wave-private LDS k tiles, no barriers needed within pass).
// Pass 2: recompute energy per tile, p = exp(e - M)*invS, accumulate acc[64].
// All hot-loop LDS reads are wave-uniform addresses -> broadcast.
// ---------------------------------------------------------------------------
__global__ __launch_bounds__(256) void attn_kernel(
    const float* __restrict__ q, const float* __restrict__ kk,
    const float* __restrict__ v, const float* __restrict__ gptr,
    float* __restrict__ out)
{
    // layout (float4 units): [0,512) kt | [512,4608) vt | [4608,4736) comb
    // pass1 aliases [w*512,(w+1)*512) as wave-private k tiles.
    __shared__ float4 smem[4736];  // 74 KB -> 2 blocks/CU
    const int t    = threadIdx.x;
    const int lane = t & 63;
    const int w    = t >> 6;
    const int b    = blockIdx.x >> 6;
    const int n0   = (blockIdx.x & 63) << 6;
    const int n    = n0 + lane;

    // per-thread query vector q[b][0..31][n]
    const float* qb = q + (size_t)b * CQ * NN;
    float qreg[CQ];
    #pragma unroll
    for (int c = 0; c < CQ; ++c) qreg[c] = qb[c * NN + n];

    const float4* kg = reinterpret_cast<const float4*>(kk + (size_t)b * CQ * NN);
    const float4* vg = reinterpret_cast<const float4*>(v + (size_t)b * CH * NN);

    // ---- pass 1: exact per-query max & sum; wave w handles m-tiles [w*16, w*16+16)
    float4* myt = smem + w * 512;   // wave-private 32x64 k tile (8 KB)
    float Mw = -INFINITY, Sw = 0.f;
    #pragma unroll 1
    for (int ti = 0; ti < 16; ++ti) {
        const int m0f4 = (w * 16 + ti) * 16;
        #pragma unroll
        for (int i = 0; i < 8; ++i) {
            int idx = lane + i * 64;   // 0..511
            myt[idx] = kg[(idx >> 4) * NF4 + m0f4 + (idx & 15)];
        }
        // wave-internal producer->consumer: drain LDS writes before reads
        asm volatile("s_waitcnt vmcnt(0) lgkmcnt(0)" ::: "memory");
        #pragma unroll 1
        for (int m4 = 0; m4 < 16; ++m4) {
            float ex = 0.f, ey = 0.f, ez = 0.f, ew = 0.f;
            #pragma unroll
            for (int c = 0; c < CQ; ++c) {
                float4 kv = myt[c * 16 + m4];  // wave-uniform -> broadcast
                ex = fmaf(qreg[c], kv.x, ex);
                ey = fmaf(qreg[c], kv.y, ey);
                ez = fmaf(qreg[c], kv.z, ez);
                ew = fmaf(qreg[c], kv.w, ew);
            }
            float mx = fmaxf(fmaxf(ex, ey), fmaxf(ez, ew));
            float Mn = fmaxf(Mw, mx);
            float al = __expf(Mw - Mn);   // exp(-inf)=0 on first tile
            Sw = fmaf(Sw, al, __expf(ex - Mn) + __expf(ey - Mn) +
                              __expf(ez - Mn) + __expf(ew - Mn));
            Mw = Mn;
        }
    }
    // combine partial (Mw, Sw) across the 4 waves
    float* combM = reinterpret_cast<float*>(smem + 4608);  // 256 floats
    float* combS = combM + 256;                            // 256 floats
    combM[t] = Mw;
    combS[t] = Sw;
    __syncthreads();
    float M0 = combM[lane],       M1 = combM[64 + lane];
    float M2 = combM[128 + lane], M3 = combM[192 + lane];
    float Mf = fmaxf(fmaxf(M0, M1), fmaxf(M2, M3));
    float Sf = combS[lane]       * __expf(M0 - Mf)
             + combS[64 + lane]  * __expf(M1 - Mf)
             + combS[128 + lane] * __expf(M2 - Mf)
             + combS[192 + lane] * __expf(M3 - Mf);
    const float invS = 1.f / Sf;

    // ---- pass 2: accumulate out channels
    float acc[64];
    #pragma unroll
    for (int i = 0; i < 64; ++i) acc[i] = 0.f;
    float4* kt = smem;         // 32 x 16 f4
    float4* vt = smem + 512;   // 256 x 16 f4
    const float4* vrow = vt + w * 1024;  // this wave's 64-channel slice

    #pragma unroll 1
    for (int m0f4 = 0; m0f4 < NF4; m0f4 += 16) {
        __syncthreads();  // previous tile fully consumed
        kt[t] = kg[(t >> 4) * NF4 + m0f4 + (t & 15)];
        {
            int i1 = t + 256;
            kt[i1] = kg[(i1 >> 4) * NF4 + m0f4 + (i1 & 15)];
        }
        #pragma unroll
        for (int i = 0; i < 16; ++i) {
            int idx = t + i * 256;
            vt[idx] = vg[(idx >> 4) * NF4 + m0f4 + (idx & 15)];
        }
        __syncthreads();
        #pragma unroll 1
        for (int m4 = 0; m4 < 16; ++m4) {
            float ex = 0.f, ey = 0.f, ez = 0.f, ew = 0.f;
            #pragma unroll
            for (int c = 0; c < CQ; ++c) {
                float4 kv = kt[c * 16 + m4];  // broadcast
                ex = fmaf(qreg[c], kv.x, ex);
                ey = fmaf(qreg[c], kv.y, ey);
                ez = fmaf(qreg[c], kv.z, ez);
                ew = fmaf(qreg[c], kv.w, ew);
            }
            const float p0 = __expf(ex - Mf) * invS;
            const float p1 = __expf(ey - Mf) * invS;
            const float p2 = __expf(ez - Mf) * invS;
            const float p3 = __expf(ew - Mf) * invS;
            #pragma unroll
            for (int cc = 0; cc < 64; ++cc) {
                float4 vv = vrow[cc * 16 + m4];  // broadcast
                float s = fmaf(p0, vv.x, acc[cc]);
                s = fmaf(p1, vv.y, s);
                s = fmaf(p2, vv.z, s);
                s = fmaf(p3, vv.w, s);
                acc[cc] = s;
            }
        }
    }

    // epilogue: (1+gamma)*out, then feature squeezing floor(x*256)/256
    const float g1 = 1.f + gptr[0];
    float* ob = out + (size_t)b * CH * NN + n;
    #pragma unroll
    for (int cc = 0; cc < 64; ++cc) {
        float val = g1 * acc[cc];
        val = floorf(val * 256.f) * 0.00390625f;
        ob[(size_t)(w * 64 + cc) * NN] = val;
    }
}

// ---------------------------------------------------------------------------
extern "C" void kernel_launch(void* const* d_in, const int* in_sizes, int n_in,
                              void* d_out, int out_size, void* d_ws, size_t ws_size,
                              hipStream_t stream) {
    const float* x  = (const float*)d_in[0];
    const float* wq = (const float*)d_in[1];
    const float* bq = (const float*)d_in[2];
    const float* wk = (const float*)d_in[3];
    const float* bk = (const float*)d_in[4];
    const float* wv = (const float*)d_in[5];
    const float* bv = (const float*)d_in[6];
    const float* gm = (const float*)d_in[7];
    float* out = (float*)d_out;

    // workspace layout: q [8*32*4096] | k [8*32*4096] | v [8*256*4096] = 40 MB
    float* ws = (float*)d_ws;
    float* q = ws;
    float* k = ws + (size_t)BB * CQ * NN;
    float* v = ws + 2 * (size_t)BB * CQ * NN;

    proj_kernel<<<512, 256, 0, stream>>>(x, wq, bq, wk, bk, wv, bv, q, k, v);
    attn_kernel<<<512, 256, 0, stream>>>(q, k, v, gm, out);
}

// Round 2
// 340.328 us; speedup vs baseline: 9.6549x; 9.6549x over previous
//
#include <hip/hip_runtime.h>
#include <math.h>

namespace {
constexpr int BB  = 8;     // batch
constexpr int CH  = 256;   // channels (v dim)
constexpr int CQ  = 32;    // q/k dim
constexpr int NN  = 4096;  // H*W
constexpr int NF4 = NN / 4;
}

typedef float  f32x4  __attribute__((ext_vector_type(4)));
typedef short  bf16x8 __attribute__((ext_vector_type(8)));

#define MFMA16(a, b, c) __builtin_amdgcn_mfma_f32_16x16x32_bf16(a, b, c, 0, 0, 0)

__device__ __forceinline__ unsigned short f2bf(float x) {
    unsigned int u = __float_as_uint(x);
    u += 0x7fffu + ((u >> 16) & 1u);            // round-to-nearest-even
    return (unsigned short)(u >> 16);
}
__device__ __forceinline__ float bf2f(unsigned short h) {
    return __uint_as_float(((unsigned int)h) << 16);
}

// async 16B global -> LDS (global_load_lds_dwordx4); dest = wave base + lane*16
__device__ __forceinline__ void gload16(const void* g, void* l) {
    __builtin_amdgcn_global_load_lds(
        (const __attribute__((address_space(1))) unsigned int*)g,
        (__attribute__((address_space(3))) unsigned int*)l, 16, 0, 0);
}

// ---------------------------------------------------------------------------
// Kernel 1: q/k/v projections (fp32 VALU GEMM, near vector roofline).
// Epilogue emits MFMA-ready layouts:
//   qh/ql/kh/kl : bf16 hi/lo split, [b][n][32]  (A/B fragment rows)
//   vT          : bf16,             [b][c][4096] (B fragment rows after stage)
// ---------------------------------------------------------------------------
__global__ __launch_bounds__(256) void proj_kernel(
    const float* __restrict__ x,
    const float* __restrict__ wq, const float* __restrict__ bq,
    const float* __restrict__ wk, const float* __restrict__ bk,
    const float* __restrict__ wv, const float* __restrict__ bv,
    unsigned short* __restrict__ qh, unsigned short* __restrict__ ql,
    unsigned short* __restrict__ kh, unsigned short* __restrict__ kl,
    unsigned short* __restrict__ vt)
{
    __shared__ float4 xt[CH * 16];  // 64 KB
    const int t  = threadIdx.x;
    const int b  = blockIdx.x >> 6;
    const int n0 = (blockIdx.x & 63) << 6;

    const float4* xg = reinterpret_cast<const float4*>(x + (size_t)b * CH * NN + n0);
    for (int i = t; i < CH * 16; i += 256)
        xt[i] = xg[(size_t)(i >> 4) * NF4 + (i & 15)];
    __syncthreads();

    const int og = t >> 4;   // 0..15
    const int jq = t & 15;   // 0..15

    #pragma unroll 1
    for (int oo = 0; oo < 20; ++oo) {
        const int o = og * 20 + oo;   // 0..319
        const float* wrow;
        float bias;
        if (o < 32)      { wrow = wq + o * CH;        bias = bq[o]; }
        else if (o < 64) { wrow = wk + (o - 32) * CH; bias = bk[o - 32]; }
        else             { wrow = wv + (o - 64) * CH; bias = bv[o - 64]; }

        const float4* w4 = reinterpret_cast<const float4*>(wrow);
        float ax = 0.f, ay = 0.f, az = 0.f, aw = 0.f;
        #pragma unroll 4
        for (int c4 = 0; c4 < CH / 4; ++c4) {
            float4 wv4 = w4[c4];
            float4 x0 = xt[(c4 * 4 + 0) * 16 + jq];
            float4 x1 = xt[(c4 * 4 + 1) * 16 + jq];
            float4 x2 = xt[(c4 * 4 + 2) * 16 + jq];
            float4 x3 = xt[(c4 * 4 + 3) * 16 + jq];
            ax = fmaf(wv4.x, x0.x, ax); ax = fmaf(wv4.y, x1.x, ax);
            ax = fmaf(wv4.z, x2.x, ax); ax = fmaf(wv4.w, x3.x, ax);
            ay = fmaf(wv4.x, x0.y, ay); ay = fmaf(wv4.y, x1.y, ay);
            ay = fmaf(wv4.z, x2.y, ay); ay = fmaf(wv4.w, x3.y, ay);
            az = fmaf(wv4.x, x0.z, az); az = fmaf(wv4.y, x1.z, az);
            az = fmaf(wv4.z, x2.z, az); az = fmaf(wv4.w, x3.z, az);
            aw = fmaf(wv4.x, x0.w, aw); aw = fmaf(wv4.y, x1.w, aw);
            aw = fmaf(wv4.z, x2.w, aw); aw = fmaf(wv4.w, x3.w, aw);
        }
        float vals[4] = { ax + bias, ay + bias, az + bias, aw + bias };

        if (o < 64) {
            const bool isq = (o < 32);
            const int  oc  = o & 31;
            unsigned short* hq = (isq ? qh : kh) + ((size_t)b * NN + n0 + jq * 4) * CQ + oc;
            unsigned short* lq = (isq ? ql : kl) + ((size_t)b * NN + n0 + jq * 4) * CQ + oc;
            #pragma unroll
            for (int p = 0; p < 4; ++p) {
                unsigned short hi = f2bf(vals[p]);
                float lo = vals[p] - bf2f(hi);
                hq[p * CQ] = hi;
                lq[p * CQ] = f2bf(lo);
            }
        } else {
            ushort4 pk;
            pk.x = f2bf(vals[0]); pk.y = f2bf(vals[1]);
            pk.z = f2bf(vals[2]); pk.w = f2bf(vals[3]);
            *reinterpret_cast<ushort4*>(vt + ((size_t)b * CH + (o - 64)) * NN + n0 + jq * 4) = pk;
        }
    }
}

// ---------------------------------------------------------------------------
// Kernel 2: MFMA flash attention, two-pass softmax.
// Block = (batch via blockIdx&7 for XCD-L2 locality, 64-query tile), 4 waves.
// Wave w: E-slice queries w*16..+15 (all keys); PV out 64q x ch [w*64,w*64+64).
// ---------------------------------------------------------------------------
#define KH_OFF 0
#define KL_OFF 4096
#define VT_OFF 8192      // 32 KB (pass 1: 16 KB K buffer)
#define P_OFF  40960     // 64 rows x 144 B (72 bf16, padded) = 9216
#define SM_OFF 50176     // 64 floats

__global__ __launch_bounds__(256, 2) void attn_kernel(
    const unsigned short* __restrict__ qh, const unsigned short* __restrict__ ql,
    const unsigned short* __restrict__ kh, const unsigned short* __restrict__ kl,
    const unsigned short* __restrict__ vt, const float* __restrict__ gptr,
    float* __restrict__ out)
{
    __shared__ __align__(16) unsigned char smem[50432];
    const int t    = threadIdx.x;
    const int lane = t & 63;
    const int w    = t >> 6;
    const int l16  = lane & 15;
    const int quad = lane >> 4;
    const int b    = blockIdx.x & 7;            // batch -> XCD swizzle
    const int n0   = (blockIdx.x >> 3) << 6;    // query tile base

    // A-operand fragments for this wave's 16 queries (held all kernel)
    const size_t qrow = (size_t)b * NN + n0 + w * 16 + l16;
    const bf16x8 qhA = *(const bf16x8*)(qh + qrow * CQ + quad * 8);
    const bf16x8 qlA = *(const bf16x8*)(ql + qrow * CQ + quad * 8);

    const unsigned char* khB = (const unsigned char*)(kh + (size_t)b * NN * CQ);
    const unsigned char* klB = (const unsigned char*)(kl + (size_t)b * NN * CQ);
    const unsigned char* vtB = (const unsigned char*)(vt + (size_t)b * CH * NN);

    // ---- pass 1: per-query max of hi-only energies (stability only)
    float M[4] = { -INFINITY, -INFINITY, -INFINITY, -INFINITY };
    #pragma unroll 1
    for (int it = 0; it < 16; ++it) {
        const size_t m0b = (size_t)(it * 256) * 64;   // 256 keys * 64 B/row
        __syncthreads();
        #pragma unroll
        for (int i = 0; i < 4; ++i)
            gload16(khB + m0b + i * 4096 + t * 16, smem + VT_OFF + i * 4096 + t * 16);
        __syncthreads();
        #pragma unroll
        for (int kt = 0; kt < 16; ++kt) {
            bf16x8 bh = *(const bf16x8*)(smem + VT_OFF + (kt * 16 + l16) * 64 + quad * 16);
            f32x4 e = { 0.f, 0.f, 0.f, 0.f };
            e = MFMA16(qhA, bh, e);
            #pragma unroll
            for (int r = 0; r < 4; ++r) M[r] = fmaxf(M[r], e[r]);
        }
    }
    #pragma unroll
    for (int mask = 1; mask <= 8; mask <<= 1) {
        #pragma unroll
        for (int r = 0; r < 4; ++r) M[r] = fmaxf(M[r], __shfl_xor(M[r], mask));
    }

    // ---- pass 2: P = exp(E - M) (bf16), S = sum(P), acc += P @ V
    f32x4 acc[4][4] = {};
    float S[4] = { 0.f, 0.f, 0.f, 0.f };

    #pragma unroll 1
    for (int tile = 0; tile < 64; ++tile) {
        const int m0 = tile * 64;
        __syncthreads();   // previous tile fully consumed
        gload16(khB + (size_t)m0 * 64 + t * 16, smem + KH_OFF + t * 16);
        gload16(klB + (size_t)m0 * 64 + t * 16, smem + KL_OFF + t * 16);
        #pragma unroll
        for (int i = 0; i < 8; ++i) {
            int gidx = i * 256 + t;
            int r = gidx >> 3, c = gidx & 7;
            int c2 = c ^ (r & 7);                 // XOR swizzle vs 128B-row banks
            gload16(vtB + (size_t)r * 8192 + (size_t)m0 * 2 + c2 * 16,
                    smem + VT_OFF + gidx * 16);
        }
        __syncthreads();

        // energies (hi/lo split: qh*kh + ql*kh + qh*kl) -> P tile in LDS
        #pragma unroll
        for (int kt = 0; kt < 4; ++kt) {
            bf16x8 bh = *(const bf16x8*)(smem + KH_OFF + (kt * 16 + l16) * 64 + quad * 16);
            bf16x8 bl = *(const bf16x8*)(smem + KL_OFF + (kt * 16 + l16) * 64 + quad * 16);
            f32x4 e = { 0.f, 0.f, 0.f, 0.f };
            e = MFMA16(qhA, bh, e);
            e = MFMA16(qlA, bh, e);
            e = MFMA16(qhA, bl, e);
            #pragma unroll
            for (int r = 0; r < 4; ++r) {
                float p = __expf(e[r] - M[r]);
                unsigned short pb = f2bf(p);
                S[r] += bf2f(pb);                 // numerator-consistent S
                *(unsigned short*)(smem + P_OFF + (w * 16 + quad * 4 + r) * 144
                                        + (kt * 16 + l16) * 2) = pb;
            }
        }
        __syncthreads();

        // PV: acc[qt][ct] += P[qt, ks] @ V[ks, ct]
        #pragma unroll
        for (int ks = 0; ks < 2; ++ks) {
            bf16x8 af[4], bfr[4];
            #pragma unroll
            for (int qt = 0; qt < 4; ++qt)
                af[qt] = *(const bf16x8*)(smem + P_OFF + (qt * 16 + l16) * 144
                                               + ks * 64 + quad * 16);
            #pragma unroll
            for (int ct = 0; ct < 4; ++ct) {
                int row = w * 64 + ct * 16 + l16;
                int ch  = (ks * 4 + quad) ^ (l16 & 7);
                bfr[ct] = *(const bf16x8*)(smem + VT_OFF + row * 128 + ch * 16);
            }
            #pragma unroll
            for (int qt = 0; qt < 4; ++qt) {
                #pragma unroll
                for (int ct = 0; ct < 4; ++ct)
                    acc[qt][ct] = MFMA16(af[qt], bfr[ct], acc[qt][ct]);
            }
        }
    }

    // ---- epilogue: reduce S, share invS, scale, squeeze, store
    #pragma unroll
    for (int mask = 1; mask <= 8; mask <<= 1) {
        #pragma unroll
        for (int r = 0; r < 4; ++r) S[r] += __shfl_xor(S[r], mask);
    }
    float* SM = (float*)(smem + SM_OFF);
    if (l16 == 0) {
        #pragma unroll
        for (int r = 0; r < 4; ++r) SM[w * 16 + quad * 4 + r] = 1.f / S[r];
    }
    __syncthreads();

    const float g1 = 1.f + gptr[0];
    float* ob = out + (size_t)b * CH * NN;
    #pragma unroll
    for (int qt = 0; qt < 4; ++qt) {
        float is[4];
        #pragma unroll
        for (int r = 0; r < 4; ++r) is[r] = SM[qt * 16 + quad * 4 + r] * g1;
        #pragma unroll
        for (int ct = 0; ct < 4; ++ct) {
            float4 o4;
            o4.x = floorf(acc[qt][ct][0] * is[0] * 256.f) * 0.00390625f;
            o4.y = floorf(acc[qt][ct][1] * is[1] * 256.f) * 0.00390625f;
            o4.z = floorf(acc[qt][ct][2] * is[2] * 256.f) * 0.00390625f;
            o4.w = floorf(acc[qt][ct][3] * is[3] * 256.f) * 0.00390625f;
            // 16 full 64B lines per instr: rows c, 16 consecutive q per row
            *(float4*)(ob + (size_t)(w * 64 + ct * 16 + l16) * NN
                          + n0 + qt * 16 + quad * 4) = o4;
        }
    }
}

// ---------------------------------------------------------------------------
extern "C" void kernel_launch(void* const* d_in, const int* in_sizes, int n_in,
                              void* d_out, int out_size, void* d_ws, size_t ws_size,
                              hipStream_t stream) {
    const float* x  = (const float*)d_in[0];
    const float* wq = (const float*)d_in[1];
    const float* bq = (const float*)d_in[2];
    const float* wk = (const float*)d_in[3];
    const float* bk = (const float*)d_in[4];
    const float* wv = (const float*)d_in[5];
    const float* bv = (const float*)d_in[6];
    const float* gm = (const float*)d_in[7];
    float* out = (float*)d_out;

    // ws: qh|ql|kh|kl [8][4096][32] bf16 (2 MB each) + vT [8][256][4096] bf16 (16 MB)
    unsigned short* ws = (unsigned short*)d_ws;
    const size_t qkN = (size_t)BB * NN * CQ;
    unsigned short* qh = ws;
    unsigned short* ql = ws + qkN;
    unsigned short* kh = ws + 2 * qkN;
    unsigned short* kl = ws + 3 * qkN;
    unsigned short* vt = ws + 4 * qkN;

    proj_kernel<<<512, 256, 0, stream>>>(x, wq, bq, wk, bk, wv, bv,
                                         qh, ql, kh, kl, vt);
    attn_kernel<<<512, 256, 0, stream>>>(qh, ql, kh, kl, vt, gm, out);
}

// Round 3
// 244.594 us; speedup vs baseline: 13.4339x; 1.3914x over previous
//
#include <hip/hip_runtime.h>
#include <math.h>

namespace {
constexpr int BB = 8;
constexpr int CH = 256;
constexpr int CQ = 32;
constexpr int NN = 4096;
}

typedef float f32x4 __attribute__((ext_vector_type(4)));
typedef short bf16x8 __attribute__((ext_vector_type(8)));
typedef unsigned short us8 __attribute__((ext_vector_type(8)));

#define MFMA16(a, b, c) __builtin_amdgcn_mfma_f32_16x16x32_bf16(a, b, c, 0, 0, 0)

__device__ __forceinline__ unsigned short f2bf(float x) {
    unsigned int u = __float_as_uint(x);
    u += 0x7fffu + ((u >> 16) & 1u);
    return (unsigned short)(u >> 16);
}
__device__ __forceinline__ float bf2f(unsigned short h) {
    return __uint_as_float(((unsigned int)h) << 16);
}
__device__ __forceinline__ void gload16(const void* g, void* l) {
    __builtin_amdgcn_global_load_lds(
        (const __attribute__((address_space(1))) unsigned int*)g,
        (__attribute__((address_space(3))) unsigned int*)l, 16, 0, 0);
}

// ---------------------------------------------------------------------------
// Kernel 0: split W (wq|wk|wv concat, 320x256) into bf16 hi/lo.
// ---------------------------------------------------------------------------
__global__ __launch_bounds__(256) void wsplit_kernel(
    const float* __restrict__ wq, const float* __restrict__ wk,
    const float* __restrict__ wv,
    unsigned short* __restrict__ wh, unsigned short* __restrict__ wl)
{
    int idx = blockIdx.x * 256 + threadIdx.x;   // 0..81919
    float v;
    if (idx < 8192)       v = wq[idx];
    else if (idx < 16384) v = wk[idx - 8192];
    else                  v = wv[idx - 16384];
    unsigned short hi = f2bf(v);
    wh[idx] = hi;
    wl[idx] = f2bf(v - bf2f(hi));
}

// ---------------------------------------------------------------------------
// Kernel 1: transpose+split X [b][256c][4096n] fp32 -> Xh/Xl [b][n][256c] bf16.
// Tile 64c x 64n per block; fully coalesced both sides via LDS.
// ---------------------------------------------------------------------------
__global__ __launch_bounds__(256) void transpose_kernel(
    const float* __restrict__ x,
    unsigned short* __restrict__ xh, unsigned short* __restrict__ xl)
{
    __shared__ float xf[64 * 68];                 // fp32 tile, padded rows
    __shared__ unsigned short hs[64 * 80];        // bf16 [n][64c] padded
    __shared__ unsigned short ls[64 * 80];
    const int t  = threadIdx.x;
    const int b  = blockIdx.x >> 8;
    const int tl = blockIdx.x & 255;
    const int c0 = (tl >> 6) * 64;
    const int n0 = (tl & 63) * 64;

    #pragma unroll
    for (int i = 0; i < 4; ++i) {
        int idx = i * 256 + t;
        int c = idx >> 4, nf = idx & 15;
        float4 v4 = *(const float4*)(x + ((size_t)(b * 256 + c0 + c)) * NN + n0 + nf * 4);
        *(float4*)(xf + c * 68 + nf * 4) = v4;
    }
    __syncthreads();

    const int n = t & 63;
    #pragma unroll
    for (int loop = 0; loop < 2; ++loop) {
        int chunk = (t >> 6) + 4 * loop;          // 0..7 (8 c's each)
        us8 h8, l8;
        #pragma unroll
        for (int j = 0; j < 8; ++j) {
            float v = xf[(chunk * 8 + j) * 68 + n];
            unsigned short hi = f2bf(v);
            h8[j] = hi;
            l8[j] = f2bf(v - bf2f(hi));
        }
        *(us8*)(hs + n * 80 + chunk * 8) = h8;
        *(us8*)(ls + n * 80 + chunk * 8) = l8;
    }
    __syncthreads();

    // copy-out: thread t -> row n=t>>2, 32B piece t&3; coalesced global writes
    {
        int rn = t >> 2, piece = t & 3;
        size_t grow = ((size_t)(b * NN + n0 + rn)) * 256 + c0 + piece * 16;
        *(f32x4*)((float*)0 + 0);  // no-op guard removed by compiler
        *(us8*)(xh + grow)     = *(const us8*)(hs + rn * 80 + piece * 16);
        *(us8*)(xh + grow + 8) = *(const us8*)(hs + rn * 80 + piece * 16 + 8);
        *(us8*)(xl + grow)     = *(const us8*)(ls + rn * 80 + piece * 16);
        *(us8*)(xl + grow + 8) = *(const us8*)(ls + rn * 80 + piece * 16 + 8);
    }
}

// ---------------------------------------------------------------------------
// Kernel 2: proj GEMM via MFMA. D[och][pixel] = (Wh+Wl)(Xh+Xl) 3-MFMA split.
// Block = (b, 64-pixel tile). Wave w owns och-tiles w*5..w*5+4 (och 0..319:
// 0-31 q, 32-63 k, 64-319 v). Epilogue -> qh/ql/kh/kl [b][n][32], vt [b][c][n].
// ---------------------------------------------------------------------------
#define PJ_XL 32768
#define PJ_VE 16384
__global__ __launch_bounds__(256, 2) void proj_kernel(
    const unsigned short* __restrict__ xh, const unsigned short* __restrict__ xl,
    const unsigned short* __restrict__ wh, const unsigned short* __restrict__ wl,
    const float* __restrict__ bq, const float* __restrict__ bk,
    const float* __restrict__ bv,
    unsigned short* __restrict__ qh, unsigned short* __restrict__ ql,
    unsigned short* __restrict__ kh, unsigned short* __restrict__ kl,
    unsigned short* __restrict__ vt)
{
    __shared__ __align__(16) unsigned char smem[65536];
    const int t    = threadIdx.x;
    const int lane = t & 63;
    const int w    = t >> 6;
    const int l16  = lane & 15;
    const int quad = lane >> 4;
    const int b    = blockIdx.x >> 6;
    const int n0   = (blockIdx.x & 63) << 6;

    // stage Xh/Xl tile [64n][256c] with chunk-XOR swizzle (rows 512B)
    const unsigned char* xhB = (const unsigned char*)(xh + ((size_t)b * NN + n0) * 256);
    const unsigned char* xlB = (const unsigned char*)(xl + ((size_t)b * NN + n0) * 256);
    #pragma unroll
    for (int j = 0; j < 8; ++j) {
        int idx = j * 256 + t;
        int r = idx >> 5, cl = idx & 31;
        int cg = cl ^ (r & 7);
        gload16(xhB + (size_t)r * 512 + cg * 16, smem + idx * 16);
        gload16(xlB + (size_t)r * 512 + cg * 16, smem + PJ_XL + idx * 16);
    }
    __syncthreads();

    f32x4 acc[5][4] = {};
    #pragma unroll 1
    for (int kc = 0; kc < 8; ++kc) {
        bf16x8 ah[5], al[5];
        #pragma unroll
        for (int i = 0; i < 5; ++i) {
            int och = (w * 5 + i) * 16 + l16;
            ah[i] = *(const bf16x8*)(wh + och * 256 + kc * 32 + quad * 8);
            al[i] = *(const bf16x8*)(wl + och * 256 + kc * 32 + quad * 8);
        }
        #pragma unroll
        for (int nt = 0; nt < 4; ++nt) {
            int roff = (nt * 16 + l16) * 512 + (((kc * 4 + quad) ^ (l16 & 7)) * 16);
            bf16x8 bh = *(const bf16x8*)(smem + roff);
            bf16x8 bl = *(const bf16x8*)(smem + PJ_XL + roff);
            #pragma unroll
            for (int i = 0; i < 5; ++i) {
                acc[i][nt] = MFMA16(ah[i], bh, acc[i][nt]);
                acc[i][nt] = MFMA16(al[i], bh, acc[i][nt]);
                acc[i][nt] = MFMA16(ah[i], bl, acc[i][nt]);
            }
        }
    }
    __syncthreads();   // main-loop LDS reads done; alias epilogue regions

    // epilogue: bias add, split/pack into LDS, then coalesced copy-out
    #pragma unroll
    for (int i = 0; i < 5; ++i) {
        int tile = w * 5 + i;
        if (tile < 4) {  // q/k tiles (wave 0 only)
            #pragma unroll
            for (int r = 0; r < 4; ++r) {
                int och = tile * 16 + quad * 4 + r;
                float bias = (och < 32) ? bq[och] : bk[och - 32];
                int arr = (och < 32) ? 0 : 2;
                int oq = och & 31;
                #pragma unroll
                for (int nt = 0; nt < 4; ++nt) {
                    float val = acc[i][nt][r] + bias;
                    unsigned short hi = f2bf(val);
                    unsigned short lo = f2bf(val - bf2f(hi));
                    *(unsigned short*)(smem + arr * 4096 + (nt * 16 + l16) * 64 + oq * 2) = hi;
                    *(unsigned short*)(smem + (arr + 1) * 4096 + (nt * 16 + l16) * 64 + oq * 2) = lo;
                }
            }
        } else {          // v tiles
            #pragma unroll
            for (int r = 0; r < 4; ++r) {
                int voch = tile * 16 + quad * 4 + r - 64;
                float bias = bv[voch];
                #pragma unroll
                for (int nt = 0; nt < 4; ++nt) {
                    *(unsigned short*)(smem + PJ_VE + voch * 136 + (nt * 16 + l16) * 2)
                        = f2bf(acc[i][nt][r] + bias);
                }
            }
        }
    }
    __syncthreads();

    // copy-out q/k: 4 arrays x 64 rows x 64B
    {
        unsigned short* dsts[4] = { qh, ql, kh, kl };
        int arr = t >> 6, n = t & 63;
        unsigned short* dst = dsts[arr] + ((size_t)b * NN + n0 + n) * 32;
        #pragma unroll
        for (int i = 0; i < 4; ++i)
            *(us8*)(dst + i * 8) = *(const us8*)(smem + arr * 4096 + n * 64 + i * 16);
    }
    // copy-out v: 256 rows x 128B, 32B pieces for coalescing
    #pragma unroll
    for (int p = 0; p < 4; ++p) {
        int voch = p * 64 + (t >> 2), piece = t & 3;
        unsigned short* dst = vt + ((size_t)b * CH + voch) * NN + n0 + piece * 16;
        *(us8*)(dst)     = *(const us8*)(smem + PJ_VE + voch * 136 + piece * 32);
        *(us8*)(dst + 8) = *(const us8*)(smem + PJ_VE + voch * 136 + piece * 32 + 16);
    }
}

// ---------------------------------------------------------------------------
// Kernel 3: MFMA flash attention, single pass (no max: |e| << 88, fp32-safe).
// Block = (b via &7 XCD swizzle, 64-query tile), 4 waves.
// E: wave w computes its 16 keys x all 64 queries (no K-read redundancy).
// PV: wave w computes all 64 queries x its 64 channels.
// K tiles staged with (row>>1)&3 chunk-XOR swizzle; V with row&7 swizzle.
// ---------------------------------------------------------------------------
#define A_KH 0
#define A_KL 4096
#define A_V  8192      // 32 KB
#define A_P  40960     // 64 x 144B
#define A_SM 50176     // 256 floats

__global__ __launch_bounds__(256, 2) void attn_kernel(
    const unsigned short* __restrict__ qh, const unsigned short* __restrict__ ql,
    const unsigned short* __restrict__ kh, const unsigned short* __restrict__ kl,
    const unsigned short* __restrict__ vt, const float* __restrict__ gptr,
    float* __restrict__ out)
{
    __shared__ __align__(16) unsigned char smem[51200];
    const int t    = threadIdx.x;
    const int lane = t & 63;
    const int w    = t >> 6;
    const int l16  = lane & 15;
    const int quad = lane >> 4;
    const int b    = blockIdx.x & 7;
    const int n0   = (blockIdx.x >> 3) << 6;

    // A-frags for all 4 query sub-tiles (hi/lo)
    bf16x8 qhA[4], qlA[4];
    #pragma unroll
    for (int qt = 0; qt < 4; ++qt) {
        size_t row = (size_t)b * NN + n0 + qt * 16 + l16;
        qhA[qt] = *(const bf16x8*)(qh + row * 32 + quad * 8);
        qlA[qt] = *(const bf16x8*)(ql + row * 32 + quad * 8);
    }

    const unsigned char* khB = (const unsigned char*)(kh + (size_t)b * NN * 32);
    const unsigned char* klB = (const unsigned char*)(kl + (size_t)b * NN * 32);
    const unsigned char* vtB = (const unsigned char*)(vt + (size_t)b * CH * NN);

    f32x4 acc[4][4] = {};
    float S[4][4] = {};

    #pragma unroll 1
    for (int tile = 0; tile < 64; ++tile) {
        const int m0 = tile * 64;
        __syncthreads();
        {   // stage kh/kl: 64 keys x 64B, chunk swizzle c ^ ((r>>1)&3)
            int r = t >> 2, cl = t & 3;
            int cg = cl ^ ((r >> 1) & 3);
            gload16(khB + (size_t)(m0 + r) * 64 + cg * 16, smem + A_KH + t * 16);
            gload16(klB + (size_t)(m0 + r) * 64 + cg * 16, smem + A_KL + t * 16);
        }
        #pragma unroll
        for (int j = 0; j < 8; ++j) {  // stage V^T: 256ch x 128B, c ^ (r&7)
            int idx = j * 256 + t;
            int r = idx >> 3, cl = idx & 7;
            int cg = cl ^ (r & 7);
            gload16(vtB + (size_t)r * 8192 + (size_t)m0 * 2 + cg * 16,
                    smem + A_V + idx * 16);
        }
        __syncthreads();

        // E: wave w's 16 keys; B-frag row = w*16+l16
        {
            int row = w * 16 + l16;
            int koff = row * 64 + ((quad ^ ((l16 >> 1) & 3)) * 16);
            bf16x8 bh = *(const bf16x8*)(smem + A_KH + koff);
            bf16x8 bl = *(const bf16x8*)(smem + A_KL + koff);
            #pragma unroll
            for (int qt = 0; qt < 4; ++qt) {
                f32x4 e = { 0.f, 0.f, 0.f, 0.f };
                e = MFMA16(qhA[qt], bh, e);
                e = MFMA16(qlA[qt], bh, e);
                e = MFMA16(qhA[qt], bl, e);
                #pragma unroll
                for (int r = 0; r < 4; ++r) {
                    float p = __expf(e[r]);
                    unsigned short pb = f2bf(p);
                    S[qt][r] += bf2f(pb);
                    *(unsigned short*)(smem + A_P + (qt * 16 + quad * 4 + r) * 144
                                            + (w * 16 + l16) * 2) = pb;
                }
            }
        }
        __syncthreads();

        // PV
        #pragma unroll
        for (int ks = 0; ks < 2; ++ks) {
            bf16x8 af[4], bfr[4];
            #pragma unroll
            for (int qt = 0; qt < 4; ++qt)
                af[qt] = *(const bf16x8*)(smem + A_P + (qt * 16 + l16) * 144
                                               + ks * 64 + quad * 16);
            #pragma unroll
            for (int ct = 0; ct < 4; ++ct) {
                int row = w * 64 + ct * 16 + l16;
                int ch = (ks * 4 + quad) ^ (l16 & 7);
                bfr[ct] = *(const bf16x8*)(smem + A_V + row * 128 + ch * 16);
            }
            #pragma unroll
            for (int qt = 0; qt < 4; ++qt)
                #pragma unroll
                for (int ct = 0; ct < 4; ++ct)
                    acc[qt][ct] = MFMA16(af[qt], bfr[ct], acc[qt][ct]);
        }
    }

    // reduce S over key-lanes, then across waves via LDS
    #pragma unroll
    for (int mask = 1; mask <= 8; mask <<= 1)
        #pragma unroll
        for (int qt = 0; qt < 4; ++qt)
            #pragma unroll
            for (int r = 0; r < 4; ++r)
                S[qt][r] += __shfl_xor(S[qt][r], mask);
    float* SM = (float*)(smem + A_SM);
    if (l16 == 0) {
        #pragma unroll
        for (int qt = 0; qt < 4; ++qt)
            #pragma unroll
            for (int r = 0; r < 4; ++r)
                SM[w * 64 + qt * 16 + quad * 4 + r] = S[qt][r];
    }
    __syncthreads();

    const float g1 = 1.f + gptr[0];
    float* ob = out + (size_t)b * CH * NN;
    #pragma unroll
    for (int qt = 0; qt < 4; ++qt) {
        float is[4];
        #pragma unroll
        for (int r = 0; r < 4; ++r) {
            int qi = qt * 16 + quad * 4 + r;
            float Sf = SM[qi] + SM[64 + qi] + SM[128 + qi] + SM[192 + qi];
            is[r] = g1 / Sf;
        }
        #pragma unroll
        for (int ct = 0; ct < 4; ++ct) {
            float4 o4;
            o4.x = floorf(acc[qt][ct][0] * is[0] * 256.f) * 0.00390625f;
            o4.y = floorf(acc[qt][ct][1] * is[1] * 256.f) * 0.00390625f;
            o4.z = floorf(acc[qt][ct][2] * is[2] * 256.f) * 0.00390625f;
            o4.w = floorf(acc[qt][ct][3] * is[3] * 256.f) * 0.00390625f;
            *(float4*)(ob + (size_t)(w * 64 + ct * 16 + l16) * NN
                          + n0 + qt * 16 + quad * 4) = o4;
        }
    }
}

// ---------------------------------------------------------------------------
extern "C" void kernel_launch(void* const* d_in, const int* in_sizes, int n_in,
                              void* d_out, int out_size, void* d_ws, size_t ws_size,
                              hipStream_t stream) {
    const float* x  = (const float*)d_in[0];
    const float* wq = (const float*)d_in[1];
    const float* bq = (const float*)d_in[2];
    const float* wk = (const float*)d_in[3];
    const float* bk = (const float*)d_in[4];
    const float* wv = (const float*)d_in[5];
    const float* bv = (const float*)d_in[6];
    const float* gm = (const float*)d_in[7];
    float* out = (float*)d_out;

    unsigned short* ws = (unsigned short*)d_ws;
    const size_t XSZ = (size_t)BB * NN * 256;   // 8,388,608
    const size_t WSZ = 320 * 256;               // 81,920
    const size_t QSZ = (size_t)BB * NN * 32;    // 1,048,576
    unsigned short* xh = ws;
    unsigned short* xl = xh + XSZ;
    unsigned short* wh = xl + XSZ;
    unsigned short* wl = wh + WSZ;
    unsigned short* qh = wl + WSZ;
    unsigned short* ql = qh + QSZ;
    unsigned short* kh = ql + QSZ;
    unsigned short* kl = kh + QSZ;
    unsigned short* vt = kl + QSZ;

    wsplit_kernel<<<320, 256, 0, stream>>>(wq, wk, wv, wh, wl);
    transpose_kernel<<<2048, 256, 0, stream>>>(x, xh, xl);
    proj_kernel<<<512, 256, 0, stream>>>(xh, xl, wh, wl, bq, bk, bv,
                                         qh, ql, kh, kl, vt);
    attn_kernel<<<512, 256, 0, stream>>>(qh, ql, kh, kl, vt, gm, out);
}